// Round 7
// baseline (100.822 us; speedup 1.0000x reference)
//
#include <hip/hip_runtime.h>
#include <math.h>

#define Bb 8
#define Tt 1000
#define TPAD 1024
#define NHh 8
#define Dd 64

typedef short bf16x8 __attribute__((ext_vector_type(8)));
typedef float f32x4 __attribute__((ext_vector_type(4)));

#define QOFF (-0.3f)
#define QSTEP (0.6f / 256.0f)
#define QINV (256.0f / 0.6f)
// p = exp2(CQ * sad)  where score = -(1/8)*STEP*sad
#define CQ (-0.125f * 1.44269504088896341f * QSTEP)

__device__ __forceinline__ unsigned sad_u8(unsigned a, unsigned b, unsigned c) {
#if __has_builtin(__builtin_amdgcn_sad_u8)
    return __builtin_amdgcn_sad_u8(a, b, c);
#else
    unsigned d;
    asm("v_sad_u8 %0, %1, %2, %3" : "=v"(d) : "v"(a), "v"(b), "v"(c));
    return d;
#endif
}

__device__ __forceinline__ unsigned quant8(float v) {
    float t = (v - QOFF) * QINV + 0.5f;
    t = fminf(fmaxf(t, 0.0f), 255.0f);
    return (unsigned)(int)t;
}

__device__ __forceinline__ unsigned cvt_pk_bf16(float lo, float hi) {
    unsigned r;
    asm("v_cvt_pk_bf16_f32 %0, %1, %2" : "=v"(r) : "v"(lo), "v"(hi));
    return r;
}

__device__ __forceinline__ bf16x8 mkbf(unsigned u0, unsigned u1, unsigned u2, unsigned u3) {
    union { unsigned u[4]; bf16x8 v; } x;
    x.u[0] = u0; x.u[1] = u1; x.u[2] = u2; x.u[3] = u3;
    return x.v;
}

__device__ __forceinline__ bf16x8 bfc(uint4 q) {
    union { uint4 q; bf16x8 v; } x; x.q = q; return x.v;
}

// async global->LDS, 16B per lane, dest = wave-uniform base + lane*16
#define GLDS(gsrc, ldst) \
    __builtin_amdgcn_global_load_lds((const __attribute__((address_space(1))) unsigned*)(gsrc), \
                                     (__attribute__((address_space(3))) unsigned*)(ldst), 16, 0, 0)

// ---------------- Kernel A: prep ----------------
// cb<8: q GEMM -> qq8 (u8, packed 4/dword, [bh][1024][16]dw)
//        + k quantize -> kq8, chunk positions PRE-SWIZZLED (c ^ ((row>>3)&3)) so the
//          attention kernel can stage tiles linearly with global_load_lds.
// cb>=8: v GEMM -> vfrag bf16 B-fragment layout [bh][st][kk*4+n][lane] of 16B
__global__ __launch_bounds__(256) void prep_kernel(
    const float* __restrict__ x, const float* __restrict__ wq,
    const float* __restrict__ wv, const float* __restrict__ wk,
    unsigned* __restrict__ qq8, unsigned* __restrict__ kq8,
    uint4* __restrict__ vfrag)
{
    __shared__ float xs[64][68];
    __shared__ float ws[64][65];
    __shared__ float vS[64][68];
    const int tid = threadIdx.x;
    const int st = blockIdx.x;      // 0..15 token tile within (b)
    const int cb = blockIdx.y;      // 0..15
    const int b  = blockIdx.z;
    const bool isQ = (cb < 8);
    const int h = isQ ? cb : (cb - 8);
    const float* W = isQ ? wq : wv;
    const int cBase = h * 64;
    const int bh = b * NHh + h;

#pragma unroll
    for (int i = 0; i < 4; ++i) {
        int f4 = tid + i * 256;
        int r = f4 >> 4, c4 = (f4 & 15) << 2;
        int row = st * 64 + r; if (row >= Tt) row = Tt - 1;
        *(float4*)&xs[r][c4] = *(const float4*)&x[((size_t)b * Tt + row) * 64 + c4];
    }
#pragma unroll
    for (int i = 0; i < 16; ++i) {
        int idx = tid + i * 256;
        int c = idx >> 6, k = idx & 63;
        ws[c][k] = W[(cBase + c) * 65 + k];
    }
    __syncthreads();

    const int rg = tid >> 4, cg = tid & 15;
    const int r0 = rg * 4, c0 = cg * 4;
    float acc[4][4];
#pragma unroll
    for (int j = 0; j < 4; ++j) {
        float bias = W[(cBase + c0 + j) * 65 + 64];
#pragma unroll
        for (int i = 0; i < 4; ++i) acc[i][j] = bias;
    }
    for (int k0 = 0; k0 < 64; k0 += 4) {
        float4 a[4];
#pragma unroll
        for (int i = 0; i < 4; ++i) a[i] = *(const float4*)&xs[r0 + i][k0];
#pragma unroll
        for (int j = 0; j < 4; ++j) {
            float b0 = ws[c0 + j][k0 + 0];
            float b1 = ws[c0 + j][k0 + 1];
            float b2 = ws[c0 + j][k0 + 2];
            float b3 = ws[c0 + j][k0 + 3];
#pragma unroll
            for (int i = 0; i < 4; ++i)
                acc[i][j] += a[i].x * b0 + a[i].y * b1 + a[i].z * b2 + a[i].w * b3;
        }
    }

    if (isQ) {
        // q -> qq8
#pragma unroll
        for (int i = 0; i < 4; ++i) {
            int t = st * 64 + r0 + i;
            unsigned d = 0u;
            if (t < Tt)
                d = quant8(acc[i][0]) | (quant8(acc[i][1]) << 8) |
                    (quant8(acc[i][2]) << 16) | (quant8(acc[i][3]) << 24);
            qq8[((size_t)bh * TPAD + t) * 16 + cg] = d;
        }
        // k = x*wk[h] -> kq8 : thread handles row tid>>2, 16 w's at (tid&3)*16
        {
            const int r = tid >> 2, c4 = tid & 3;
            const int t = st * 64 + r;
            unsigned kd[4];
            if (t < Tt) {
#pragma unroll
                for (int dw = 0; dw < 4; ++dw) {
                    int w = c4 * 16 + dw * 4;
                    float4 wkv = *(const float4*)&wk[h * 64 + w];
                    kd[dw] = quant8(xs[r][w + 0] * wkv.x) |
                             (quant8(xs[r][w + 1] * wkv.y) << 8) |
                             (quant8(xs[r][w + 2] * wkv.z) << 16) |
                             (quant8(xs[r][w + 3] * wkv.w) << 24);
                }
            } else {
                kd[0] = kd[1] = kd[2] = kd[3] = 0u;
            }
            // pre-swizzled chunk position: linear LDS staging + conflict-free group reads
            const int c4s = c4 ^ ((r >> 3) & 3);
            *(uint4*)&kq8[((size_t)bh * TPAD + t) * 16 + c4s * 4] =
                make_uint4(kd[0], kd[1], kd[2], kd[3]);
        }
    } else {
        // v -> vS -> bf16 fragment layout
#pragma unroll
        for (int i = 0; i < 4; ++i) {
            float4 o; o.x = acc[i][0]; o.y = acc[i][1]; o.z = acc[i][2]; o.w = acc[i][3];
            *(float4*)&vS[r0 + i][c0] = o;
        }
        __syncthreads();
#pragma unroll
        for (int e2 = 0; e2 < 2; ++e2) {
            int ent = tid + e2 * 256;       // 0..511 = kk*256 + n*64 + lane
            int kk = ent >> 8, rem = ent & 255, n = rem >> 6, lane = rem & 63;
            int ts = kk * 32 + ((lane >> 4) << 3);
            int w  = n * 16 + (lane & 15);
            unsigned o[4];
#pragma unroll
            for (int pr = 0; pr < 4; ++pr) {
                int t0 = st * 64 + ts + pr * 2;
                float lo = (t0 < Tt)     ? vS[ts + pr * 2][w]     : 0.0f;
                float hi = (t0 + 1 < Tt) ? vS[ts + pr * 2 + 1][w] : 0.0f;
                o[pr] = cvt_pk_bf16(lo, hi);
            }
            vfrag[(((size_t)bh * 16 + st) * 8 + (kk * 4 + n)) * 64 + lane] =
                make_uint4(o[0], o[1], o[2], o[3]);
        }
    }
}

// ---------------- Kernel B: attention ----------------
// Block = 128 threads (2 waves), 64 q-rows. Each wave owns 32 q-rows: lane l handles
// tq_a = rowbase + (l&15) and tq_b = rowbase + 16 + (l&15) — the 64 k-LDS-reads per
// tile now feed 512 SADs (2x amortization vs round 6; LDS return bus was the pipe limit).
// Tiles staged with global_load_lds (k layout pre-swizzled by prep), double-buffered.
__global__ __launch_bounds__(128) void attn_kernel(
    const unsigned* __restrict__ qq8, const unsigned* __restrict__ kq8,
    const uint4* __restrict__ vfrag, float* __restrict__ part)
{
    __shared__ unsigned kS[2][1024];   // 4 KB per buf
    __shared__ uint4    vS[2][512];    // 8 KB per buf

    const int tid = threadIdx.x;       // 0..127
    const int wv_ = tid >> 6;          // wave 0..1
    const int l   = tid & 63;
    const int g   = l >> 4;            // 0..3
    const int m   = l & 15;
    const int qt  = blockIdx.x;        // 0..15
    const int h   = blockIdx.y, b = blockIdx.z;
    const int bh  = b * NHh + h;
    const int rowbase = qt * 64 + wv_ * 32;

    // two q rows per lane (16 dw each)
    unsigned qa[16], qb[16];
    {
        const uint4* qp = (const uint4*)qq8 + ((size_t)bh * TPAD + rowbase + m) * 4;
        *(uint4*)&qa[0]  = qp[0];  *(uint4*)&qa[4]  = qp[1];
        *(uint4*)&qa[8]  = qp[2];  *(uint4*)&qa[12] = qp[3];
        const uint4* qp2 = qp + 16 * 4;    // +16 rows
        *(uint4*)&qb[0]  = qp2[0]; *(uint4*)&qb[4]  = qp2[1];
        *(uint4*)&qb[8]  = qp2[2]; *(uint4*)&qb[12] = qp2[3];
    }

    const uint4* kg = (const uint4*)kq8 + (size_t)bh * 4096;  // tile t at +t*256
    const uint4* vg = vfrag + (size_t)bh * 8192;              // tile t at +t*512

    // prologue: stage tile 0 into buf 0
    {
        const uint4* kt = kg;
        const uint4* vt = vg;
        GLDS(kt + wv_ * 64 +   0 + l, &kS[0][(wv_ * 64 +   0) * 4]);
        GLDS(kt + wv_ * 64 + 128 + l, &kS[0][(wv_ * 64 + 128) * 4]);
        GLDS(vt + wv_ * 64 +   0 + l, &vS[0][wv_ * 64 +   0]);
        GLDS(vt + wv_ * 64 + 128 + l, &vS[0][wv_ * 64 + 128]);
        GLDS(vt + wv_ * 64 + 256 + l, &vS[0][wv_ * 64 + 256]);
        GLDS(vt + wv_ * 64 + 384 + l, &vS[0][wv_ * 64 + 384]);
    }
    __syncthreads();

    f32x4 aca[4], acb[4];
#pragma unroll
    for (int n = 0; n < 4; ++n) { aca[n] = (f32x4){0.f,0.f,0.f,0.f}; acb[n] = aca[n]; }
    float dsum_a = 0.0f, dsum_b = 0.0f;

#pragma unroll 1
    for (int t = 0; t < 16; ++t) {
        const int cur = t & 1;

        // issue next-tile async stages (land in buf^1 during this tile's compute)
        if (t < 15) {
            const uint4* kt = kg + (t + 1) * 256;
            const uint4* vt = vg + (t + 1) * 512;
            GLDS(kt + wv_ * 64 +   0 + l, &kS[cur ^ 1][(wv_ * 64 +   0) * 4]);
            GLDS(kt + wv_ * 64 + 128 + l, &kS[cur ^ 1][(wv_ * 64 + 128) * 4]);
            GLDS(vt + wv_ * 64 +   0 + l, &vS[cur ^ 1][wv_ * 64 +   0]);
            GLDS(vt + wv_ * 64 + 128 + l, &vS[cur ^ 1][wv_ * 64 + 128]);
            GLDS(vt + wv_ * 64 + 256 + l, &vS[cur ^ 1][wv_ * 64 + 256]);
            GLDS(vt + wv_ * 64 + 384 + l, &vS[cur ^ 1][wv_ * 64 + 384]);
        }

#pragma unroll
        for (int kk = 0; kk < 2; ++kk) {
            unsigned ca[8], cb[8];
#pragma unroll
            for (int e = 0; e < 8; ++e) {
                const unsigned* kb = &kS[cur][(kk * 32 + (g << 3) + e) << 4];
                uint4 c0 = *(const uint4*)(kb + ((0 ^ g) << 2));
                uint4 c1 = *(const uint4*)(kb + ((1 ^ g) << 2));
                uint4 c2 = *(const uint4*)(kb + ((2 ^ g) << 2));
                uint4 c3 = *(const uint4*)(kb + ((3 ^ g) << 2));
                const unsigned* k0 = (const unsigned*)&c0;
                const unsigned* k1 = (const unsigned*)&c1;
                const unsigned* k2 = (const unsigned*)&c2;
                const unsigned* k3 = (const unsigned*)&c3;
                unsigned sa0 = 0u, sa1 = 0u, sb0 = 0u, sb1 = 0u;
#pragma unroll
                for (int w = 0; w < 4; ++w) {
                    sa0 = sad_u8(qa[w],      k0[w], sa0);
                    sa1 = sad_u8(qa[4 + w],  k1[w], sa1);
                    sb0 = sad_u8(qb[w],      k0[w], sb0);
                    sb1 = sad_u8(qb[4 + w],  k1[w], sb1);
                }
#pragma unroll
                for (int w = 0; w < 4; ++w) {
                    sa0 = sad_u8(qa[8 + w],  k2[w], sa0);
                    sa1 = sad_u8(qa[12 + w], k3[w], sa1);
                    sb0 = sad_u8(qb[8 + w],  k2[w], sb0);
                    sb1 = sad_u8(qb[12 + w], k3[w], sb1);
                }
                ca[e] = sa0 + sa1;
                cb[e] = sb0 + sb1;
            }

            const bool maskall = (t == 15) && (kk == 1) && (g >= 1);
            float pa[8], pb[8];
#pragma unroll
            for (int e = 0; e < 8; ++e) {
                pa[e] = maskall ? 0.0f : __builtin_amdgcn_exp2f(CQ * (float)ca[e]);
                pb[e] = maskall ? 0.0f : __builtin_amdgcn_exp2f(CQ * (float)cb[e]);
                dsum_a += pa[e];
                dsum_b += pb[e];
            }
            bf16x8 Aa = mkbf(cvt_pk_bf16(pa[0], pa[1]), cvt_pk_bf16(pa[2], pa[3]),
                             cvt_pk_bf16(pa[4], pa[5]), cvt_pk_bf16(pa[6], pa[7]));
            bf16x8 Ab = mkbf(cvt_pk_bf16(pb[0], pb[1]), cvt_pk_bf16(pb[2], pb[3]),
                             cvt_pk_bf16(pb[4], pb[5]), cvt_pk_bf16(pb[6], pb[7]));

            // 4 V fragments serve both q-row halves
            uint4 vf0 = vS[cur][(kk * 4 + 0) * 64 + l];
            uint4 vf1 = vS[cur][(kk * 4 + 1) * 64 + l];
            uint4 vf2 = vS[cur][(kk * 4 + 2) * 64 + l];
            uint4 vf3 = vS[cur][(kk * 4 + 3) * 64 + l];
            aca[0] = __builtin_amdgcn_mfma_f32_16x16x32_bf16(Aa, bfc(vf0), aca[0], 0, 0, 0);
            acb[0] = __builtin_amdgcn_mfma_f32_16x16x32_bf16(Ab, bfc(vf0), acb[0], 0, 0, 0);
            aca[1] = __builtin_amdgcn_mfma_f32_16x16x32_bf16(Aa, bfc(vf1), aca[1], 0, 0, 0);
            acb[1] = __builtin_amdgcn_mfma_f32_16x16x32_bf16(Ab, bfc(vf1), acb[1], 0, 0, 0);
            aca[2] = __builtin_amdgcn_mfma_f32_16x16x32_bf16(Aa, bfc(vf2), aca[2], 0, 0, 0);
            acb[2] = __builtin_amdgcn_mfma_f32_16x16x32_bf16(Ab, bfc(vf2), acb[2], 0, 0, 0);
            aca[3] = __builtin_amdgcn_mfma_f32_16x16x32_bf16(Aa, bfc(vf3), aca[3], 0, 0, 0);
            acb[3] = __builtin_amdgcn_mfma_f32_16x16x32_bf16(Ab, bfc(vf3), acb[3], 0, 0, 0);
        }

        __syncthreads();   // drains async stages (vmcnt) + publishes buf^1
    }

    // denominators: reduce over the 4 lane-groups sharing m; +1 for the null row
    dsum_a += __shfl_xor(dsum_a, 16);
    dsum_a += __shfl_xor(dsum_a, 32);
    dsum_b += __shfl_xor(dsum_b, 16);
    dsum_b += __shfl_xor(dsum_b, 32);
    const float den_a = 1.0f + dsum_a;
    const float den_b = 1.0f + dsum_b;

    // store: rows rowbase + g*4+j (a-half) and rowbase + 16 + g*4+j (b-half); col n*16 + m
#pragma unroll
    for (int j = 0; j < 4; ++j) {
        float dja = __shfl(den_a, g * 4 + j);
        float djb = __shfl(den_b, g * 4 + j);
        int row_a = rowbase + g * 4 + j;
        int row_b = rowbase + 16 + g * 4 + j;
        if (row_a < Tt) {
            float inv = 1.0f / dja;
            float* o = part + (((size_t)b * Tt + row_a) * NHh + h) * 64 + m;
            o[0]  = aca[0][j] * inv;
            o[16] = aca[1][j] * inv;
            o[32] = aca[2][j] * inv;
            o[48] = aca[3][j] * inv;
        }
        if (row_b < Tt) {
            float inv = 1.0f / djb;
            float* o = part + (((size_t)b * Tt + row_b) * NHh + h) * 64 + m;
            o[0]  = acb[0][j] * inv;
            o[16] = acb[1][j] * inv;
            o[32] = acb[2][j] * inv;
            o[48] = acb[3][j] * inv;
        }
    }
}

// ---------------- Kernel C: head-sum + ReLU + wf projection + residual ----------
__global__ __launch_bounds__(256) void finalize_kernel(
    const float* __restrict__ x, const float* __restrict__ wf,
    const float* __restrict__ part, float* __restrict__ out)
{
    __shared__ float wfs[64][65];
    __shared__ float osh[4][64];
    const int tid = threadIdx.x;
    for (int i = tid; i < 64 * 65; i += 256) wfs[i / 65][i % 65] = wf[i];
    const int wave = tid >> 6, lane = tid & 63;
    const int token = blockIdx.x * 4 + wave;   // 0..7999
    float o = 0.f;
    const float* pt = part + (size_t)token * NHh * Dd;
#pragma unroll
    for (int hh = 0; hh < NHh; ++hh) o += pt[hh * Dd + lane];
    o = fmaxf(o, 0.f);
    osh[wave][lane] = o;
    __syncthreads();
    float acc = wfs[lane][64];    // bias
#pragma unroll 8
    for (int w = 0; w < 64; ++w) acc += wfs[lane][w] * osh[wave][w];
    out[(size_t)token * Dd + lane] = x[(size_t)token * Dd + lane] + acc;
}

extern "C" void kernel_launch(void* const* d_in, const int* in_sizes, int n_in,
                              void* d_out, int out_size, void* d_ws, size_t ws_size,
                              hipStream_t stream)
{
    const float* x  = (const float*)d_in[0];
    const float* wq = (const float*)d_in[1];
    const float* wv = (const float*)d_in[2];
    const float* wk = (const float*)d_in[3];
    const float* wf = (const float*)d_in[4];
    float* out = (float*)d_out;

    char* base = (char*)d_ws;
    float*    part  = (float*)base;                                   // 16,384,000 B
    unsigned* qq8   = (unsigned*)(base + 16384000);                   //  4,194,304 B
    unsigned* kq8   = (unsigned*)(base + 16384000 + 4194304);         //  4,194,304 B
    uint4*    vfrag = (uint4*)(base + 16384000 + 2 * 4194304);        //  8,388,608 B

    prep_kernel<<<dim3(16, 16, Bb), 256, 0, stream>>>(x, wq, wv, wk, qq8, kq8, vfrag);
    attn_kernel<<<dim3(16, NHh, Bb), 128, 0, stream>>>(qq8, kq8, vfrag, part);
    finalize_kernel<<<2000, 256, 0, stream>>>(x, wf, part, out);
}

// Round 8
// 96.461 us; speedup vs baseline: 1.0452x; 1.0452x over previous
//
#include <hip/hip_runtime.h>
#include <math.h>

#define Bb 8
#define Tt 1000
#define TPAD 1024
#define NHh 8
#define Dd 64

typedef short bf16x8 __attribute__((ext_vector_type(8)));
typedef float f32x4 __attribute__((ext_vector_type(4)));

#define QOFF (-0.3f)
#define QSTEP (0.6f / 256.0f)
#define QINV (256.0f / 0.6f)
// p = exp2(CQ * sad)  where score = -(1/8)*STEP*sad
#define CQ (-0.125f * 1.44269504088896341f * QSTEP)

__device__ __forceinline__ unsigned sad_u8(unsigned a, unsigned b, unsigned c) {
#if __has_builtin(__builtin_amdgcn_sad_u8)
    return __builtin_amdgcn_sad_u8(a, b, c);
#else
    unsigned d;
    asm("v_sad_u8 %0, %1, %2, %3" : "=v"(d) : "v"(a), "v"(b), "v"(c));
    return d;
#endif
}

__device__ __forceinline__ unsigned quant8(float v) {
    float t = (v - QOFF) * QINV + 0.5f;
    t = fminf(fmaxf(t, 0.0f), 255.0f);
    return (unsigned)(int)t;
}

__device__ __forceinline__ unsigned cvt_pk_bf16(float lo, float hi) {
    unsigned r;
    asm("v_cvt_pk_bf16_f32 %0, %1, %2" : "=v"(r) : "v"(lo), "v"(hi));
    return r;
}

__device__ __forceinline__ bf16x8 mkbf(unsigned u0, unsigned u1, unsigned u2, unsigned u3) {
    union { unsigned u[4]; bf16x8 v; } x;
    x.u[0] = u0; x.u[1] = u1; x.u[2] = u2; x.u[3] = u3;
    return x.v;
}

__device__ __forceinline__ bf16x8 bfc(uint4 q) {
    union { uint4 q; bf16x8 v; } x; x.q = q; return x.v;
}

// async global->LDS, 16B per lane, dest = wave-uniform base + lane*16
#define GLDS(gsrc, ldst) \
    __builtin_amdgcn_global_load_lds((const __attribute__((address_space(1))) unsigned*)(gsrc), \
                                     (__attribute__((address_space(3))) unsigned*)(ldst), 16, 0, 0)

// ---------------- Kernel A: prep ----------------
// cb<8: q GEMM -> qq8 (u8, packed 4/dword, [bh][1024][16]dw)
//        + k quantize -> kq8, chunk positions PRE-SWIZZLED (c ^ ((row>>3)&3)) so the
//          attention kernel can stage tiles linearly with global_load_lds.
// cb>=8: v GEMM -> vfrag bf16 B-fragment layout [bh][st][kk*4+n][lane] of 16B
__global__ __launch_bounds__(256) void prep_kernel(
    const float* __restrict__ x, const float* __restrict__ wq,
    const float* __restrict__ wv, const float* __restrict__ wk,
    unsigned* __restrict__ qq8, unsigned* __restrict__ kq8,
    uint4* __restrict__ vfrag)
{
    __shared__ float xs[64][68];
    __shared__ float ws[64][65];
    __shared__ float vS[64][68];
    const int tid = threadIdx.x;
    const int st = blockIdx.x;      // 0..15 token tile within (b)
    const int cb = blockIdx.y;      // 0..15
    const int b  = blockIdx.z;
    const bool isQ = (cb < 8);
    const int h = isQ ? cb : (cb - 8);
    const float* W = isQ ? wq : wv;
    const int cBase = h * 64;
    const int bh = b * NHh + h;

#pragma unroll
    for (int i = 0; i < 4; ++i) {
        int f4 = tid + i * 256;
        int r = f4 >> 4, c4 = (f4 & 15) << 2;
        int row = st * 64 + r; if (row >= Tt) row = Tt - 1;
        *(float4*)&xs[r][c4] = *(const float4*)&x[((size_t)b * Tt + row) * 64 + c4];
    }
#pragma unroll
    for (int i = 0; i < 16; ++i) {
        int idx = tid + i * 256;
        int c = idx >> 6, k = idx & 63;
        ws[c][k] = W[(cBase + c) * 65 + k];
    }
    __syncthreads();

    const int rg = tid >> 4, cg = tid & 15;
    const int r0 = rg * 4, c0 = cg * 4;
    float acc[4][4];
#pragma unroll
    for (int j = 0; j < 4; ++j) {
        float bias = W[(cBase + c0 + j) * 65 + 64];
#pragma unroll
        for (int i = 0; i < 4; ++i) acc[i][j] = bias;
    }
    for (int k0 = 0; k0 < 64; k0 += 4) {
        float4 a[4];
#pragma unroll
        for (int i = 0; i < 4; ++i) a[i] = *(const float4*)&xs[r0 + i][k0];
#pragma unroll
        for (int j = 0; j < 4; ++j) {
            float b0 = ws[c0 + j][k0 + 0];
            float b1 = ws[c0 + j][k0 + 1];
            float b2 = ws[c0 + j][k0 + 2];
            float b3 = ws[c0 + j][k0 + 3];
#pragma unroll
            for (int i = 0; i < 4; ++i)
                acc[i][j] += a[i].x * b0 + a[i].y * b1 + a[i].z * b2 + a[i].w * b3;
        }
    }

    if (isQ) {
        // q -> qq8
#pragma unroll
        for (int i = 0; i < 4; ++i) {
            int t = st * 64 + r0 + i;
            unsigned d = 0u;
            if (t < Tt)
                d = quant8(acc[i][0]) | (quant8(acc[i][1]) << 8) |
                    (quant8(acc[i][2]) << 16) | (quant8(acc[i][3]) << 24);
            qq8[((size_t)bh * TPAD + t) * 16 + cg] = d;
        }
        // k = x*wk[h] -> kq8 : thread handles row tid>>2, 16 w's at (tid&3)*16
        {
            const int r = tid >> 2, c4 = tid & 3;
            const int t = st * 64 + r;
            unsigned kd[4];
            if (t < Tt) {
#pragma unroll
                for (int dw = 0; dw < 4; ++dw) {
                    int w = c4 * 16 + dw * 4;
                    float4 wkv = *(const float4*)&wk[h * 64 + w];
                    kd[dw] = quant8(xs[r][w + 0] * wkv.x) |
                             (quant8(xs[r][w + 1] * wkv.y) << 8) |
                             (quant8(xs[r][w + 2] * wkv.z) << 16) |
                             (quant8(xs[r][w + 3] * wkv.w) << 24);
                }
            } else {
                kd[0] = kd[1] = kd[2] = kd[3] = 0u;
            }
            // pre-swizzled chunk position: linear LDS staging + conflict-free group reads
            const int c4s = c4 ^ ((r >> 3) & 3);
            *(uint4*)&kq8[((size_t)bh * TPAD + t) * 16 + c4s * 4] =
                make_uint4(kd[0], kd[1], kd[2], kd[3]);
        }
    } else {
        // v -> vS -> bf16 fragment layout
#pragma unroll
        for (int i = 0; i < 4; ++i) {
            float4 o; o.x = acc[i][0]; o.y = acc[i][1]; o.z = acc[i][2]; o.w = acc[i][3];
            *(float4*)&vS[r0 + i][c0] = o;
        }
        __syncthreads();
#pragma unroll
        for (int e2 = 0; e2 < 2; ++e2) {
            int ent = tid + e2 * 256;       // 0..511 = kk*256 + n*64 + lane
            int kk = ent >> 8, rem = ent & 255, n = rem >> 6, lane = rem & 63;
            int ts = kk * 32 + ((lane >> 4) << 3);
            int w  = n * 16 + (lane & 15);
            unsigned o[4];
#pragma unroll
            for (int pr = 0; pr < 4; ++pr) {
                int t0 = st * 64 + ts + pr * 2;
                float lo = (t0 < Tt)     ? vS[ts + pr * 2][w]     : 0.0f;
                float hi = (t0 + 1 < Tt) ? vS[ts + pr * 2 + 1][w] : 0.0f;
                o[pr] = cvt_pk_bf16(lo, hi);
            }
            vfrag[(((size_t)bh * 16 + st) * 8 + (kk * 4 + n)) * 64 + lane] =
                make_uint4(o[0], o[1], o[2], o[3]);
        }
    }
}

// ---------------- Kernel B: attention, triple-buffered LDS + counted vmcnt ----------------
// Block = 64 q-rows, 4 waves; wave w owns rows qt*64 + w*16 + (0..15).
// Tile t issues 3 GLDS/wave for tile t+2 (exact coverage: 1 k + 2 v per wave);
// barrier = s_waitcnt vmcnt(3) + raw s_barrier -> only tile t+1's stages must have
// landed; t+2's stay in flight ACROSS the barrier (m201 counted-vmcnt pattern).
__global__ __launch_bounds__(256) void attn_kernel(
    const unsigned* __restrict__ qq8, const unsigned* __restrict__ kq8,
    const uint4* __restrict__ vfrag, float* __restrict__ part)
{
    __shared__ unsigned kS[3][1024];   // 4 KB per buf
    __shared__ uint4    vS[3][512];    // 8 KB per buf  (total 36 KB)

    const int tid = threadIdx.x;
    const int wv_ = tid >> 6;          // wave 0..3
    const int l   = tid & 63;
    const int g   = l >> 4;            // 0..3
    const int m   = l & 15;
    const int qt  = blockIdx.x;        // 0..15
    const int h   = blockIdx.y, b = blockIdx.z;
    const int bh  = b * NHh + h;

    // q row (16 dwords = 64 u8); rows >=1000 are garbage but their outputs are masked at store
    unsigned qv[16];
    {
        const uint4* qp = (const uint4*)(qq8 + ((size_t)bh * TPAD + qt * 64 + wv_ * 16 + m) * 16);
        *(uint4*)&qv[0]  = qp[0];
        *(uint4*)&qv[4]  = qp[1];
        *(uint4*)&qv[8]  = qp[2];
        *(uint4*)&qv[12] = qp[3];
    }

    const uint4* kg = (const uint4*)kq8 + (size_t)bh * 4096;  // tile t at +t*256
    const uint4* vg = vfrag + (size_t)bh * 8192;              // tile t at +t*512

    // exact-coverage stage of tile TT into buffer SB: each wave 1 k-GLDS + 2 v-GLDS
#define STAGE(TT, SB) do { \
        const uint4* kt_ = kg + (TT) * 256; \
        const uint4* vt_ = vg + (TT) * 512; \
        GLDS(kt_ + wv_ * 64 + l,       &kS[SB][(wv_ * 64) * 4]); \
        GLDS(vt_ + wv_ * 128 + l,      &vS[SB][wv_ * 128]); \
        GLDS(vt_ + wv_ * 128 + 64 + l, &vS[SB][wv_ * 128 + 64]); \
    } while (0)

    // prologue: stage tiles 0 and 1; wait only tile 0 (oldest 3 of 6)
    STAGE(0, 0);
    STAGE(1, 1);
    asm volatile("s_waitcnt vmcnt(3)" ::: "memory");
    __builtin_amdgcn_s_barrier();
    __builtin_amdgcn_sched_barrier(0);

    f32x4 acc0 = {0.f,0.f,0.f,0.f}, acc1 = acc0, acc2 = acc0, acc3 = acc0;
    float dsum = 0.0f;

    int cur = 0, stb = 2;
#pragma unroll 1
    for (int t = 0; t < 16; ++t) {
        // issue tile t+2's stages (3 GLDS) — stay in flight across the next barrier
        if (t < 14) STAGE(t + 2, stb);

        // ---- scores from LDS k tile
        bf16x8 A0, A1;
#pragma unroll
        for (int kk = 0; kk < 2; ++kk) {
            unsigned accu[8];
#pragma unroll
            for (int e = 0; e < 8; ++e) {
                const unsigned* kb = &kS[cur][(kk * 32 + (g << 3) + e) << 4];
                uint4 c0 = *(const uint4*)(kb + ((0 ^ g) << 2));
                uint4 c1 = *(const uint4*)(kb + ((1 ^ g) << 2));
                uint4 c2 = *(const uint4*)(kb + ((2 ^ g) << 2));
                uint4 c3 = *(const uint4*)(kb + ((3 ^ g) << 2));
                const unsigned* k0 = (const unsigned*)&c0;
                const unsigned* k1 = (const unsigned*)&c1;
                const unsigned* k2 = (const unsigned*)&c2;
                const unsigned* k3 = (const unsigned*)&c3;
                unsigned sa = 0u, sb = 0u;
#pragma unroll
                for (int w = 0; w < 4; ++w) sa = sad_u8(qv[w],      k0[w], sa);
#pragma unroll
                for (int w = 0; w < 4; ++w) sb = sad_u8(qv[4 + w],  k1[w], sb);
#pragma unroll
                for (int w = 0; w < 4; ++w) sa = sad_u8(qv[8 + w],  k2[w], sa);
#pragma unroll
                for (int w = 0; w < 4; ++w) sb = sad_u8(qv[12 + w], k3[w], sb);
                accu[e] = sa + sb;
            }
            const bool maskall = (t == 15) && (kk == 1) && (g >= 1);
            float p[8];
#pragma unroll
            for (int e = 0; e < 8; ++e) {
                p[e] = maskall ? 0.0f : __builtin_amdgcn_exp2f(CQ * (float)accu[e]);
                dsum += p[e];
            }
            bf16x8 A = mkbf(cvt_pk_bf16(p[0], p[1]), cvt_pk_bf16(p[2], p[3]),
                            cvt_pk_bf16(p[4], p[5]), cvt_pk_bf16(p[6], p[7]));
            if (kk == 0) A0 = A; else A1 = A;
        }

        // ---- PV via MFMA, V fragments from LDS (two halves of 4)
        {
            uint4 vf0 = vS[cur][0 * 64 + l], vf1 = vS[cur][1 * 64 + l];
            uint4 vf2 = vS[cur][2 * 64 + l], vf3 = vS[cur][3 * 64 + l];
            acc0 = __builtin_amdgcn_mfma_f32_16x16x32_bf16(A0, bfc(vf0), acc0, 0, 0, 0);
            acc1 = __builtin_amdgcn_mfma_f32_16x16x32_bf16(A0, bfc(vf1), acc1, 0, 0, 0);
            acc2 = __builtin_amdgcn_mfma_f32_16x16x32_bf16(A0, bfc(vf2), acc2, 0, 0, 0);
            acc3 = __builtin_amdgcn_mfma_f32_16x16x32_bf16(A0, bfc(vf3), acc3, 0, 0, 0);
        }
        {
            uint4 vf4 = vS[cur][4 * 64 + l], vf5 = vS[cur][5 * 64 + l];
            uint4 vf6 = vS[cur][6 * 64 + l], vf7 = vS[cur][7 * 64 + l];
            acc0 = __builtin_amdgcn_mfma_f32_16x16x32_bf16(A1, bfc(vf4), acc0, 0, 0, 0);
            acc1 = __builtin_amdgcn_mfma_f32_16x16x32_bf16(A1, bfc(vf5), acc1, 0, 0, 0);
            acc2 = __builtin_amdgcn_mfma_f32_16x16x32_bf16(A1, bfc(vf6), acc2, 0, 0, 0);
            acc3 = __builtin_amdgcn_mfma_f32_16x16x32_bf16(A1, bfc(vf7), acc3, 0, 0, 0);
        }

        // ---- counted-vmcnt barrier: require t+1's stages landed; keep t+2's in flight
        if (t < 14) {
            asm volatile("s_waitcnt vmcnt(3)" ::: "memory");
        } else if (t == 14) {
            asm volatile("s_waitcnt vmcnt(0)" ::: "memory");
        }
        if (t < 15) {
            __builtin_amdgcn_s_barrier();
            __builtin_amdgcn_sched_barrier(0);
        }
        cur = (cur == 2) ? 0 : cur + 1;
        stb = (stb == 2) ? 0 : stb + 1;
    }
#undef STAGE

    // denominator: sum over the 4 lane-groups sharing m; +1 for the null row
    dsum += __shfl_xor(dsum, 16);
    dsum += __shfl_xor(dsum, 32);
    const float den = 1.0f + dsum;     // valid per lane for q-row index m

    // store: q-row = qt*64 + wv_*16 + g*4 + j, col = n*16 + m (accn)
#pragma unroll
    for (int j = 0; j < 4; ++j) {
        float dj = __shfl(den, g * 4 + j);
        int row = qt * 64 + wv_ * 16 + g * 4 + j;
        if (row < Tt) {
            float inv = 1.0f / dj;
            float* o = part + (((size_t)b * Tt + row) * NHh + h) * 64 + m;
            o[0]  = acc0[j] * inv;
            o[16] = acc1[j] * inv;
            o[32] = acc2[j] * inv;
            o[48] = acc3[j] * inv;
        }
    }
}

// ---------------- Kernel C: head-sum + ReLU + wf projection + residual ----------
__global__ __launch_bounds__(256) void finalize_kernel(
    const float* __restrict__ x, const float* __restrict__ wf,
    const float* __restrict__ part, float* __restrict__ out)
{
    __shared__ float wfs[64][65];
    __shared__ float osh[4][64];
    const int tid = threadIdx.x;
    for (int i = tid; i < 64 * 65; i += 256) wfs[i / 65][i % 65] = wf[i];
    const int wave = tid >> 6, lane = tid & 63;
    const int token = blockIdx.x * 4 + wave;   // 0..7999
    float o = 0.f;
    const float* pt = part + (size_t)token * NHh * Dd;
#pragma unroll
    for (int hh = 0; hh < NHh; ++hh) o += pt[hh * Dd + lane];
    o = fmaxf(o, 0.f);
    osh[wave][lane] = o;
    __syncthreads();
    float acc = wfs[lane][64];    // bias
#pragma unroll 8
    for (int w = 0; w < 64; ++w) acc += wfs[lane][w] * osh[wave][w];
    out[(size_t)token * Dd + lane] = x[(size_t)token * Dd + lane] + acc;
}

extern "C" void kernel_launch(void* const* d_in, const int* in_sizes, int n_in,
                              void* d_out, int out_size, void* d_ws, size_t ws_size,
                              hipStream_t stream)
{
    const float* x  = (const float*)d_in[0];
    const float* wq = (const float*)d_in[1];
    const float* wv = (const float*)d_in[2];
    const float* wk = (const float*)d_in[3];
    const float* wf = (const float*)d_in[4];
    float* out = (float*)d_out;

    char* base = (char*)d_ws;
    float*    part  = (float*)base;                                   // 16,384,000 B
    unsigned* qq8   = (unsigned*)(base + 16384000);                   //  4,194,304 B
    unsigned* kq8   = (unsigned*)(base + 16384000 + 4194304);         //  4,194,304 B
    uint4*    vfrag = (uint4*)(base + 16384000 + 2 * 4194304);        //  8,388,608 B

    prep_kernel<<<dim3(16, 16, Bb), 256, 0, stream>>>(x, wq, wv, wk, qq8, kq8, vfrag);
    attn_kernel<<<dim3(16, NHh, Bb), 256, 0, stream>>>(qq8, kq8, vfrag, part);
    finalize_kernel<<<2000, 256, 0, stream>>>(x, wf, part, out);
}

// Round 9
// 92.251 us; speedup vs baseline: 1.0929x; 1.0456x over previous
//
#include <hip/hip_runtime.h>
#include <math.h>

#define Bb 8
#define Tt 1000
#define TPAD 1024
#define NHh 8
#define Dd 64

typedef short bf16x8 __attribute__((ext_vector_type(8)));
typedef float f32x4 __attribute__((ext_vector_type(4)));

#define QOFF (-0.3f)
#define QSTEP (0.6f / 256.0f)
#define QINV (256.0f / 0.6f)
// p = exp2(CQ * sad)  where score = -(1/8)*STEP*sad
#define CQ (-0.125f * 1.44269504088896341f * QSTEP)

__device__ __forceinline__ unsigned sad_u8(unsigned a, unsigned b, unsigned c) {
#if __has_builtin(__builtin_amdgcn_sad_u8)
    return __builtin_amdgcn_sad_u8(a, b, c);
#else
    unsigned d;
    asm("v_sad_u8 %0, %1, %2, %3" : "=v"(d) : "v"(a), "v"(b), "v"(c));
    return d;
#endif
}

__device__ __forceinline__ unsigned quant8(float v) {
    float t = (v - QOFF) * QINV + 0.5f;
    t = fminf(fmaxf(t, 0.0f), 255.0f);
    return (unsigned)(int)t;
}

__device__ __forceinline__ unsigned cvt_pk_bf16(float lo, float hi) {
    unsigned r;
    asm("v_cvt_pk_bf16_f32 %0, %1, %2" : "=v"(r) : "v"(lo), "v"(hi));
    return r;
}

__device__ __forceinline__ bf16x8 mkbf(unsigned u0, unsigned u1, unsigned u2, unsigned u3) {
    union { unsigned u[4]; bf16x8 v; } x;
    x.u[0] = u0; x.u[1] = u1; x.u[2] = u2; x.u[3] = u3;
    return x.v;
}

__device__ __forceinline__ bf16x8 bfc(uint4 q) {
    union { uint4 q; bf16x8 v; } x; x.q = q; return x.v;
}

// async global->LDS, 16B per lane, dest = wave-uniform base + lane*16
#define GLDS(gsrc, ldst) \
    __builtin_amdgcn_global_load_lds((const __attribute__((address_space(1))) unsigned*)(gsrc), \
                                     (__attribute__((address_space(3))) unsigned*)(ldst), 16, 0, 0)

// ---------------- Kernel A: prep ----------------
// cb<8: q GEMM -> qq8 (u8, packed 4/dword, [bh][1024][16]dw)
//        + k quantize -> kq8, chunk positions PRE-SWIZZLED (c ^ ((row>>3)&3))
// cb>=8: v GEMM -> vfrag bf16 B-fragment layout [bh][st][kk*4+n][lane] of 16B
__global__ __launch_bounds__(256) void prep_kernel(
    const float* __restrict__ x, const float* __restrict__ wq,
    const float* __restrict__ wv, const float* __restrict__ wk,
    unsigned* __restrict__ qq8, unsigned* __restrict__ kq8,
    uint4* __restrict__ vfrag)
{
    __shared__ float xs[64][68];
    __shared__ float ws[64][65];
    __shared__ float vS[64][68];
    const int tid = threadIdx.x;
    const int st = blockIdx.x;      // 0..15 token tile within (b)
    const int cb = blockIdx.y;      // 0..15
    const int b  = blockIdx.z;
    const bool isQ = (cb < 8);
    const int h = isQ ? cb : (cb - 8);
    const float* W = isQ ? wq : wv;
    const int cBase = h * 64;
    const int bh = b * NHh + h;

#pragma unroll
    for (int i = 0; i < 4; ++i) {
        int f4 = tid + i * 256;
        int r = f4 >> 4, c4 = (f4 & 15) << 2;
        int row = st * 64 + r; if (row >= Tt) row = Tt - 1;
        *(float4*)&xs[r][c4] = *(const float4*)&x[((size_t)b * Tt + row) * 64 + c4];
    }
#pragma unroll
    for (int i = 0; i < 16; ++i) {
        int idx = tid + i * 256;
        int c = idx >> 6, k = idx & 63;
        ws[c][k] = W[(cBase + c) * 65 + k];
    }
    __syncthreads();

    const int rg = tid >> 4, cg = tid & 15;
    const int r0 = rg * 4, c0 = cg * 4;
    float acc[4][4];
#pragma unroll
    for (int j = 0; j < 4; ++j) {
        float bias = W[(cBase + c0 + j) * 65 + 64];
#pragma unroll
        for (int i = 0; i < 4; ++i) acc[i][j] = bias;
    }
    for (int k0 = 0; k0 < 64; k0 += 4) {
        float4 a[4];
#pragma unroll
        for (int i = 0; i < 4; ++i) a[i] = *(const float4*)&xs[r0 + i][k0];
#pragma unroll
        for (int j = 0; j < 4; ++j) {
            float b0 = ws[c0 + j][k0 + 0];
            float b1 = ws[c0 + j][k0 + 1];
            float b2 = ws[c0 + j][k0 + 2];
            float b3 = ws[c0 + j][k0 + 3];
#pragma unroll
            for (int i = 0; i < 4; ++i)
                acc[i][j] += a[i].x * b0 + a[i].y * b1 + a[i].z * b2 + a[i].w * b3;
        }
    }

    if (isQ) {
#pragma unroll
        for (int i = 0; i < 4; ++i) {
            int t = st * 64 + r0 + i;
            unsigned d = 0u;
            if (t < Tt)
                d = quant8(acc[i][0]) | (quant8(acc[i][1]) << 8) |
                    (quant8(acc[i][2]) << 16) | (quant8(acc[i][3]) << 24);
            qq8[((size_t)bh * TPAD + t) * 16 + cg] = d;
        }
        {
            const int r = tid >> 2, c4 = tid & 3;
            const int t = st * 64 + r;
            unsigned kd[4];
            if (t < Tt) {
#pragma unroll
                for (int dw = 0; dw < 4; ++dw) {
                    int w = c4 * 16 + dw * 4;
                    float4 wkv = *(const float4*)&wk[h * 64 + w];
                    kd[dw] = quant8(xs[r][w + 0] * wkv.x) |
                             (quant8(xs[r][w + 1] * wkv.y) << 8) |
                             (quant8(xs[r][w + 2] * wkv.z) << 16) |
                             (quant8(xs[r][w + 3] * wkv.w) << 24);
                }
            } else {
                kd[0] = kd[1] = kd[2] = kd[3] = 0u;
            }
            const int c4s = c4 ^ ((r >> 3) & 3);
            *(uint4*)&kq8[((size_t)bh * TPAD + t) * 16 + c4s * 4] =
                make_uint4(kd[0], kd[1], kd[2], kd[3]);
        }
    } else {
#pragma unroll
        for (int i = 0; i < 4; ++i) {
            float4 o; o.x = acc[i][0]; o.y = acc[i][1]; o.z = acc[i][2]; o.w = acc[i][3];
            *(float4*)&vS[r0 + i][c0] = o;
        }
        __syncthreads();
#pragma unroll
        for (int e2 = 0; e2 < 2; ++e2) {
            int ent = tid + e2 * 256;       // 0..511 = kk*256 + n*64 + lane
            int kk = ent >> 8, rem = ent & 255, n = rem >> 6, lane = rem & 63;
            int ts = kk * 32 + ((lane >> 4) << 3);
            int w  = n * 16 + (lane & 15);
            unsigned o[4];
#pragma unroll
            for (int pr = 0; pr < 4; ++pr) {
                int t0 = st * 64 + ts + pr * 2;
                float lo = (t0 < Tt)     ? vS[ts + pr * 2][w]     : 0.0f;
                float hi = (t0 + 1 < Tt) ? vS[ts + pr * 2 + 1][w] : 0.0f;
                o[pr] = cvt_pk_bf16(lo, hi);
            }
            vfrag[(((size_t)bh * 16 + st) * 8 + (kk * 4 + n)) * 64 + lane] =
                make_uint4(o[0], o[1], o[2], o[3]);
        }
    }
}

// ---------------- Kernel B: attention, 2D wave split (rows x tiles) ----------------
// Block = 64 q-rows, 4 waves. Wave w: rowhalf=w&1 (rows rowbase..+31, lane handles m and
// m+16), tilehalf=w>>1 (source tiles th*8..th*8+7). Wave count unchanged vs r6 (16/CU),
// but each k-LDS-read now feeds 2 q-rows (512 SADs per 64 reads). V is loaded global->reg
// (per-lane distinct; no broadcast value in LDS), issued kk-half-wise so latency hides
// under SADs. Pair (w, w^2) reduces numerators+denoms via LDS (reusing k-staging region).
__global__ __launch_bounds__(256) void attn_kernel(
    const unsigned* __restrict__ qq8, const unsigned* __restrict__ kq8,
    const uint4* __restrict__ vfrag, float* __restrict__ part)
{
    __shared__ uint4 smem[1024];       // k staging: [stream][buf][256] (16 KB); reused for reduce
    __shared__ float dred[2][2][16];   // [rowhalf][rowset][m]

    const int tid = threadIdx.x;
    const int wv_ = tid >> 6;          // wave 0..3
    const int l   = tid & 63;
    const int g   = l >> 4;            // 0..3
    const int m   = l & 15;
    const int qt  = blockIdx.x;        // 0..15
    const int h   = blockIdx.y, b = blockIdx.z;
    const int bh  = b * NHh + h;
    const int rowhalf  = wv_ & 1;
    const int tilehalf = wv_ >> 1;
    const int rowbase  = qt * 64 + rowhalf * 32;

    // two q rows per lane (16 dw each): rows rowbase+m and rowbase+16+m
    unsigned qa[16], qb[16];
    {
        const uint4* qp = (const uint4*)qq8 + ((size_t)bh * TPAD + rowbase + m) * 4;
        *(uint4*)&qa[0]  = qp[0];  *(uint4*)&qa[4]  = qp[1];
        *(uint4*)&qa[8]  = qp[2];  *(uint4*)&qa[12] = qp[3];
        const uint4* qp2 = qp + 64;    // +16 rows
        *(uint4*)&qb[0]  = qp2[0]; *(uint4*)&qb[4]  = qp2[1];
        *(uint4*)&qb[8]  = qp2[2]; *(uint4*)&qb[12] = qp2[3];
    }

    const uint4* kg = (const uint4*)kq8 + (size_t)bh * 4096;  // tile t at +t*256
    const uint4* vg = vfrag + (size_t)bh * 8192;              // tile t at +t*512

    // stage k tiles I (stream 0) and 8+I (stream 1) into buffer BUF; 2 GLDS per wave
#define STAGEK(I, BUF) do { \
        GLDS(kg + (I) * 256 + wv_ * 64 + l,       &smem[(0 * 2 + (BUF)) * 256 + wv_ * 64]); \
        GLDS(kg + (8 + (I)) * 256 + wv_ * 64 + l, &smem[(1 * 2 + (BUF)) * 256 + wv_ * 64]); \
    } while (0)

    STAGEK(0, 0);
    __syncthreads();   // drains vmcnt

    f32x4 aca[4], acb[4];
#pragma unroll
    for (int n = 0; n < 4; ++n) { aca[n] = (f32x4){0.f,0.f,0.f,0.f}; acb[n] = aca[n]; }
    float dsum_a = 0.0f, dsum_b = 0.0f;

#pragma unroll 1
    for (int i = 0; i < 8; ++i) {
        const int cur = i & 1;
        const int t = tilehalf * 8 + i;               // my source tile
        const uint4* kbase = &smem[(tilehalf * 2 + cur) * 256];
        const uint4* vt = vg + (size_t)t * 512 + l;

        // issue next pair's k stages (land during this tile's compute)
        if (i < 7) STAGEK(i + 1, cur ^ 1);

        // V fragments for kk=0, issued before the SAD phase (latency hides under SADs)
        uint4 vf0 = vt[0 * 64], vf1 = vt[1 * 64], vf2 = vt[2 * 64], vf3 = vt[3 * 64];

        // ---- kk = 0
        bf16x8 Aa0, Ab0;
        {
            float pa[8], pb[8];
#pragma unroll
            for (int e = 0; e < 8; ++e) {
                const uint4* kb = kbase + ((g << 3) + e) * 4;
                uint4 c0 = kb[0 ^ g], c1 = kb[1 ^ g], c2 = kb[2 ^ g], c3 = kb[3 ^ g];
                const unsigned* k0 = (const unsigned*)&c0;
                const unsigned* k1 = (const unsigned*)&c1;
                const unsigned* k2 = (const unsigned*)&c2;
                const unsigned* k3 = (const unsigned*)&c3;
                unsigned sa0 = 0u, sa1 = 0u, sb0 = 0u, sb1 = 0u;
#pragma unroll
                for (int w = 0; w < 4; ++w) {
                    sa0 = sad_u8(qa[w],      k0[w], sa0);
                    sa1 = sad_u8(qa[4 + w],  k1[w], sa1);
                    sb0 = sad_u8(qb[w],      k0[w], sb0);
                    sb1 = sad_u8(qb[4 + w],  k1[w], sb1);
                }
#pragma unroll
                for (int w = 0; w < 4; ++w) {
                    sa0 = sad_u8(qa[8 + w],  k2[w], sa0);
                    sa1 = sad_u8(qa[12 + w], k3[w], sa1);
                    sb0 = sad_u8(qb[8 + w],  k2[w], sb0);
                    sb1 = sad_u8(qb[12 + w], k3[w], sb1);
                }
                pa[e] = __builtin_amdgcn_exp2f(CQ * (float)(sa0 + sa1));
                pb[e] = __builtin_amdgcn_exp2f(CQ * (float)(sb0 + sb1));
                dsum_a += pa[e];
                dsum_b += pb[e];
            }
            Aa0 = mkbf(cvt_pk_bf16(pa[0], pa[1]), cvt_pk_bf16(pa[2], pa[3]),
                       cvt_pk_bf16(pa[4], pa[5]), cvt_pk_bf16(pa[6], pa[7]));
            Ab0 = mkbf(cvt_pk_bf16(pb[0], pb[1]), cvt_pk_bf16(pb[2], pb[3]),
                       cvt_pk_bf16(pb[4], pb[5]), cvt_pk_bf16(pb[6], pb[7]));
        }

        // PV for kk=0
        aca[0] = __builtin_amdgcn_mfma_f32_16x16x32_bf16(Aa0, bfc(vf0), aca[0], 0, 0, 0);
        acb[0] = __builtin_amdgcn_mfma_f32_16x16x32_bf16(Ab0, bfc(vf0), acb[0], 0, 0, 0);
        aca[1] = __builtin_amdgcn_mfma_f32_16x16x32_bf16(Aa0, bfc(vf1), aca[1], 0, 0, 0);
        acb[1] = __builtin_amdgcn_mfma_f32_16x16x32_bf16(Ab0, bfc(vf1), acb[1], 0, 0, 0);
        aca[2] = __builtin_amdgcn_mfma_f32_16x16x32_bf16(Aa0, bfc(vf2), aca[2], 0, 0, 0);
        acb[2] = __builtin_amdgcn_mfma_f32_16x16x32_bf16(Ab0, bfc(vf2), acb[2], 0, 0, 0);
        aca[3] = __builtin_amdgcn_mfma_f32_16x16x32_bf16(Aa0, bfc(vf3), aca[3], 0, 0, 0);
        acb[3] = __builtin_amdgcn_mfma_f32_16x16x32_bf16(Ab0, bfc(vf3), acb[3], 0, 0, 0);

        // V fragments for kk=1
        uint4 vf4 = vt[4 * 64], vf5 = vt[5 * 64], vf6 = vt[6 * 64], vf7 = vt[7 * 64];

        // ---- kk = 1  (tile 15: rows 1000+ live in g>=1's e-range)
        bf16x8 Aa1, Ab1;
        {
            const bool maskall = (t == 15) && (g >= 1);
            float pa[8], pb[8];
#pragma unroll
            for (int e = 0; e < 8; ++e) {
                const uint4* kb = kbase + (32 + (g << 3) + e) * 4;
                uint4 c0 = kb[0 ^ g], c1 = kb[1 ^ g], c2 = kb[2 ^ g], c3 = kb[3 ^ g];
                const unsigned* k0 = (const unsigned*)&c0;
                const unsigned* k1 = (const unsigned*)&c1;
                const unsigned* k2 = (const unsigned*)&c2;
                const unsigned* k3 = (const unsigned*)&c3;
                unsigned sa0 = 0u, sa1 = 0u, sb0 = 0u, sb1 = 0u;
#pragma unroll
                for (int w = 0; w < 4; ++w) {
                    sa0 = sad_u8(qa[w],      k0[w], sa0);
                    sa1 = sad_u8(qa[4 + w],  k1[w], sa1);
                    sb0 = sad_u8(qb[w],      k0[w], sb0);
                    sb1 = sad_u8(qb[4 + w],  k1[w], sb1);
                }
#pragma unroll
                for (int w = 0; w < 4; ++w) {
                    sa0 = sad_u8(qa[8 + w],  k2[w], sa0);
                    sa1 = sad_u8(qa[12 + w], k3[w], sa1);
                    sb0 = sad_u8(qb[8 + w],  k2[w], sb0);
                    sb1 = sad_u8(qb[12 + w], k3[w], sb1);
                }
                pa[e] = maskall ? 0.0f : __builtin_amdgcn_exp2f(CQ * (float)(sa0 + sa1));
                pb[e] = maskall ? 0.0f : __builtin_amdgcn_exp2f(CQ * (float)(sb0 + sb1));
                dsum_a += pa[e];
                dsum_b += pb[e];
            }
            Aa1 = mkbf(cvt_pk_bf16(pa[0], pa[1]), cvt_pk_bf16(pa[2], pa[3]),
                       cvt_pk_bf16(pa[4], pa[5]), cvt_pk_bf16(pa[6], pa[7]));
            Ab1 = mkbf(cvt_pk_bf16(pb[0], pb[1]), cvt_pk_bf16(pb[2], pb[3]),
                       cvt_pk_bf16(pb[4], pb[5]), cvt_pk_bf16(pb[6], pb[7]));
        }

        // PV for kk=1
        aca[0] = __builtin_amdgcn_mfma_f32_16x16x32_bf16(Aa1, bfc(vf4), aca[0], 0, 0, 0);
        acb[0] = __builtin_amdgcn_mfma_f32_16x16x32_bf16(Ab1, bfc(vf4), acb[0], 0, 0, 0);
        aca[1] = __builtin_amdgcn_mfma_f32_16x16x32_bf16(Aa1, bfc(vf5), aca[1], 0, 0, 0);
        acb[1] = __builtin_amdgcn_mfma_f32_16x16x32_bf16(Ab1, bfc(vf5), acb[1], 0, 0, 0);
        aca[2] = __builtin_amdgcn_mfma_f32_16x16x32_bf16(Aa1, bfc(vf6), aca[2], 0, 0, 0);
        acb[2] = __builtin_amdgcn_mfma_f32_16x16x32_bf16(Ab1, bfc(vf6), acb[2], 0, 0, 0);
        aca[3] = __builtin_amdgcn_mfma_f32_16x16x32_bf16(Aa1, bfc(vf7), aca[3], 0, 0, 0);
        acb[3] = __builtin_amdgcn_mfma_f32_16x16x32_bf16(Ab1, bfc(vf7), acb[3], 0, 0, 0);

        __syncthreads();   // publishes next buffer; drains stages
    }
#undef STAGEK

    // intra-wave denominator reduce over the 4 lane-groups sharing m
    dsum_a += __shfl_xor(dsum_a, 16);
    dsum_a += __shfl_xor(dsum_a, 32);
    dsum_b += __shfl_xor(dsum_b, 16);
    dsum_b += __shfl_xor(dsum_b, 32);

    // cross-wave pair reduce: tilehalf-1 waves publish, tilehalf-0 waves finalize.
    f32x4* red = (f32x4*)smem;         // [rowhalf][rowset][n][64] = 1024 f32x4 (16 KB)
    if (tilehalf == 1) {
#pragma unroll
        for (int n = 0; n < 4; ++n) {
            red[(((rowhalf * 2 + 0) * 4) + n) * 64 + l] = aca[n];
            red[(((rowhalf * 2 + 1) * 4) + n) * 64 + l] = acb[n];
        }
        if (l < 16) { dred[rowhalf][0][l] = dsum_a; dred[rowhalf][1][l] = dsum_b; }
    }
    __syncthreads();
    if (tilehalf == 0) {
#pragma unroll
        for (int n = 0; n < 4; ++n) {
            f32x4 ra = red[(((rowhalf * 2 + 0) * 4) + n) * 64 + l];
            f32x4 rb = red[(((rowhalf * 2 + 1) * 4) + n) * 64 + l];
#pragma unroll
            for (int j = 0; j < 4; ++j) { aca[n][j] += ra[j]; acb[n][j] += rb[j]; }
        }
        const float den_a = 1.0f + dsum_a + dred[rowhalf][0][m];
        const float den_b = 1.0f + dsum_b + dred[rowhalf][1][m];

#pragma unroll
        for (int j = 0; j < 4; ++j) {
            float dja = __shfl(den_a, g * 4 + j);
            float djb = __shfl(den_b, g * 4 + j);
            int row_a = rowbase + g * 4 + j;
            int row_b = rowbase + 16 + g * 4 + j;
            if (row_a < Tt) {
                float inv = 1.0f / dja;
                float* o = part + (((size_t)b * Tt + row_a) * NHh + h) * 64 + m;
                o[0]  = aca[0][j] * inv;
                o[16] = aca[1][j] * inv;
                o[32] = aca[2][j] * inv;
                o[48] = aca[3][j] * inv;
            }
            if (row_b < Tt) {
                float inv = 1.0f / djb;
                float* o = part + (((size_t)b * Tt + row_b) * NHh + h) * 64 + m;
                o[0]  = acb[0][j] * inv;
                o[16] = acb[1][j] * inv;
                o[32] = acb[2][j] * inv;
                o[48] = acb[3][j] * inv;
            }
        }
    }
}

// ---------------- Kernel C: head-sum + ReLU + wf projection + residual ----------
__global__ __launch_bounds__(256) void finalize_kernel(
    const float* __restrict__ x, const float* __restrict__ wf,
    const float* __restrict__ part, float* __restrict__ out)
{
    __shared__ float wfs[64][65];
    __shared__ float osh[4][64];
    const int tid = threadIdx.x;
    for (int i = tid; i < 64 * 65; i += 256) wfs[i / 65][i % 65] = wf[i];
    const int wave = tid >> 6, lane = tid & 63;
    const int token = blockIdx.x * 4 + wave;   // 0..7999
    float o = 0.f;
    const float* pt = part + (size_t)token * NHh * Dd;
#pragma unroll
    for (int hh = 0; hh < NHh; ++hh) o += pt[hh * Dd + lane];
    o = fmaxf(o, 0.f);
    osh[wave][lane] = o;
    __syncthreads();
    float acc = wfs[lane][64];    // bias
#pragma unroll 8
    for (int w = 0; w < 64; ++w) acc += wfs[lane][w] * osh[wave][w];
    out[(size_t)token * Dd + lane] = x[(size_t)token * Dd + lane] + acc;
}

extern "C" void kernel_launch(void* const* d_in, const int* in_sizes, int n_in,
                              void* d_out, int out_size, void* d_ws, size_t ws_size,
                              hipStream_t stream)
{
    const float* x  = (const float*)d_in[0];
    const float* wq = (const float*)d_in[1];
    const float* wv = (const float*)d_in[2];
    const float* wk = (const float*)d_in[3];
    const float* wf = (const float*)d_in[4];
    float* out = (float*)d_out;

    char* base = (char*)d_ws;
    float*    part  = (float*)base;                                   // 16,384,000 B
    unsigned* qq8   = (unsigned*)(base + 16384000);                   //  4,194,304 B
    unsigned* kq8   = (unsigned*)(base + 16384000 + 4194304);         //  4,194,304 B
    uint4*    vfrag = (uint4*)(base + 16384000 + 2 * 4194304);        //  8,388,608 B

    prep_kernel<<<dim3(16, 16, Bb), 256, 0, stream>>>(x, wq, wv, wk, qq8, kq8, vfrag);
    attn_kernel<<<dim3(16, NHh, Bb), 256, 0, stream>>>(qq8, kq8, vfrag, part);
    finalize_kernel<<<2000, 256, 0, stream>>>(x, wf, part, out);
}

// Round 10
// 91.998 us; speedup vs baseline: 1.0959x; 1.0027x over previous
//
#include <hip/hip_runtime.h>
#include <math.h>

#define Bb 8
#define Tt 1000
#define TPAD 1024
#define NHh 8
#define Dd 64

typedef short bf16x8 __attribute__((ext_vector_type(8)));
typedef float f32x4 __attribute__((ext_vector_type(4)));

#define QOFF (-0.3f)
#define QSTEP (0.6f / 256.0f)
#define QINV (256.0f / 0.6f)
// p = exp2(CQ * sad)  where score = -(1/8)*STEP*sad
#define CQ (-0.125f * 1.44269504088896341f * QSTEP)

__device__ __forceinline__ unsigned sad_u8(unsigned a, unsigned b, unsigned c) {
#if __has_builtin(__builtin_amdgcn_sad_u8)
    return __builtin_amdgcn_sad_u8(a, b, c);
#else
    unsigned d;
    asm("v_sad_u8 %0, %1, %2, %3" : "=v"(d) : "v"(a), "v"(b), "v"(c));
    return d;
#endif
}

__device__ __forceinline__ unsigned quant8(float v) {
    float t = (v - QOFF) * QINV + 0.5f;
    t = fminf(fmaxf(t, 0.0f), 255.0f);
    return (unsigned)(int)t;
}

__device__ __forceinline__ unsigned cvt_pk_bf16(float lo, float hi) {
    unsigned r;
    asm("v_cvt_pk_bf16_f32 %0, %1, %2" : "=v"(r) : "v"(lo), "v"(hi));
    return r;
}

__device__ __forceinline__ unsigned short f2bf(float v) {
    return (unsigned short)(cvt_pk_bf16(v, v) & 0xffffu);
}

__device__ __forceinline__ float bf2f(unsigned short u) {
    union { unsigned u; float f; } x; x.u = ((unsigned)u) << 16; return x.f;
}

__device__ __forceinline__ bf16x8 mkbf(unsigned u0, unsigned u1, unsigned u2, unsigned u3) {
    union { unsigned u[4]; bf16x8 v; } x;
    x.u[0] = u0; x.u[1] = u1; x.u[2] = u2; x.u[3] = u3;
    return x.v;
}

__device__ __forceinline__ bf16x8 bfc(uint4 q) {
    union { uint4 q; bf16x8 v; } x; x.q = q; return x.v;
}

// async global->LDS, 16B per lane, dest = wave-uniform base + lane*16
#define GLDS(gsrc, ldst) \
    __builtin_amdgcn_global_load_lds((const __attribute__((address_space(1))) unsigned*)(gsrc), \
                                     (__attribute__((address_space(3))) unsigned*)(ldst), 16, 0, 0)

// ---------------- Kernel A: prep (unchanged from r9) ----------------
__global__ __launch_bounds__(256) void prep_kernel(
    const float* __restrict__ x, const float* __restrict__ wq,
    const float* __restrict__ wv, const float* __restrict__ wk,
    unsigned* __restrict__ qq8, unsigned* __restrict__ kq8,
    uint4* __restrict__ vfrag)
{
    __shared__ float xs[64][68];
    __shared__ float ws[64][65];
    __shared__ float vS[64][68];
    const int tid = threadIdx.x;
    const int st = blockIdx.x;      // 0..15 token tile within (b)
    const int cb = blockIdx.y;      // 0..15
    const int b  = blockIdx.z;
    const bool isQ = (cb < 8);
    const int h = isQ ? cb : (cb - 8);
    const float* W = isQ ? wq : wv;
    const int cBase = h * 64;
    const int bh = b * NHh + h;

#pragma unroll
    for (int i = 0; i < 4; ++i) {
        int f4 = tid + i * 256;
        int r = f4 >> 4, c4 = (f4 & 15) << 2;
        int row = st * 64 + r; if (row >= Tt) row = Tt - 1;
        *(float4*)&xs[r][c4] = *(const float4*)&x[((size_t)b * Tt + row) * 64 + c4];
    }
#pragma unroll
    for (int i = 0; i < 16; ++i) {
        int idx = tid + i * 256;
        int c = idx >> 6, k = idx & 63;
        ws[c][k] = W[(cBase + c) * 65 + k];
    }
    __syncthreads();

    const int rg = tid >> 4, cg = tid & 15;
    const int r0 = rg * 4, c0 = cg * 4;
    float acc[4][4];
#pragma unroll
    for (int j = 0; j < 4; ++j) {
        float bias = W[(cBase + c0 + j) * 65 + 64];
#pragma unroll
        for (int i = 0; i < 4; ++i) acc[i][j] = bias;
    }
    for (int k0 = 0; k0 < 64; k0 += 4) {
        float4 a[4];
#pragma unroll
        for (int i = 0; i < 4; ++i) a[i] = *(const float4*)&xs[r0 + i][k0];
#pragma unroll
        for (int j = 0; j < 4; ++j) {
            float b0 = ws[c0 + j][k0 + 0];
            float b1 = ws[c0 + j][k0 + 1];
            float b2 = ws[c0 + j][k0 + 2];
            float b3 = ws[c0 + j][k0 + 3];
#pragma unroll
            for (int i = 0; i < 4; ++i)
                acc[i][j] += a[i].x * b0 + a[i].y * b1 + a[i].z * b2 + a[i].w * b3;
        }
    }

    if (isQ) {
#pragma unroll
        for (int i = 0; i < 4; ++i) {
            int t = st * 64 + r0 + i;
            unsigned d = 0u;
            if (t < Tt)
                d = quant8(acc[i][0]) | (quant8(acc[i][1]) << 8) |
                    (quant8(acc[i][2]) << 16) | (quant8(acc[i][3]) << 24);
            qq8[((size_t)bh * TPAD + t) * 16 + cg] = d;
        }
        {
            const int r = tid >> 2, c4 = tid & 3;
            const int t = st * 64 + r;
            unsigned kd[4];
            if (t < Tt) {
#pragma unroll
                for (int dw = 0; dw < 4; ++dw) {
                    int w = c4 * 16 + dw * 4;
                    float4 wkv = *(const float4*)&wk[h * 64 + w];
                    kd[dw] = quant8(xs[r][w + 0] * wkv.x) |
                             (quant8(xs[r][w + 1] * wkv.y) << 8) |
                             (quant8(xs[r][w + 2] * wkv.z) << 16) |
                             (quant8(xs[r][w + 3] * wkv.w) << 24);
                }
            } else {
                kd[0] = kd[1] = kd[2] = kd[3] = 0u;
            }
            const int c4s = c4 ^ ((r >> 3) & 3);
            *(uint4*)&kq8[((size_t)bh * TPAD + t) * 16 + c4s * 4] =
                make_uint4(kd[0], kd[1], kd[2], kd[3]);
        }
    } else {
#pragma unroll
        for (int i = 0; i < 4; ++i) {
            float4 o; o.x = acc[i][0]; o.y = acc[i][1]; o.z = acc[i][2]; o.w = acc[i][3];
            *(float4*)&vS[r0 + i][c0] = o;
        }
        __syncthreads();
#pragma unroll
        for (int e2 = 0; e2 < 2; ++e2) {
            int ent = tid + e2 * 256;       // 0..511 = kk*256 + n*64 + lane
            int kk = ent >> 8, rem = ent & 255, n = rem >> 6, lane = rem & 63;
            int ts = kk * 32 + ((lane >> 4) << 3);
            int w  = n * 16 + (lane & 15);
            unsigned o[4];
#pragma unroll
            for (int pr = 0; pr < 4; ++pr) {
                int t0 = st * 64 + ts + pr * 2;
                float lo = (t0 < Tt)     ? vS[ts + pr * 2][w]     : 0.0f;
                float hi = (t0 + 1 < Tt) ? vS[ts + pr * 2 + 1][w] : 0.0f;
                o[pr] = cvt_pk_bf16(lo, hi);
            }
            vfrag[(((size_t)bh * 16 + st) * 8 + (kk * 4 + n)) * 64 + lane] =
                make_uint4(o[0], o[1], o[2], o[3]);
        }
    }
}

// ---------------- Kernel B: attention, split-K x2 across blocks ----------------
// Grid (16 qt, 8 h, 16 bz): b = bz>>1, half = bz&1; block covers source tiles
// half*8 .. half*8+7. Waves: rowhalf(w&1) x tileq(w>>1); each wave 32 q-rows
// (2/lane) x 4 tiles. Writes RAW bf16 numerators + per-half denominator sums;
// normalization and half/head summation happen in finalize.
__global__ __launch_bounds__(256) void attn_kernel(
    const unsigned* __restrict__ qq8, const unsigned* __restrict__ kq8,
    const uint4* __restrict__ vfrag,
    unsigned short* __restrict__ numbf, float* __restrict__ dsums)
{
    __shared__ uint4 smem[1024];       // k staging: [stream][buf][256] (16 KB); reused for reduce
    __shared__ float dred[2][2][16];   // [rowhalf][rowset][m]

    const int tid = threadIdx.x;
    const int wv_ = tid >> 6;          // wave 0..3
    const int l   = tid & 63;
    const int g   = l >> 4;            // 0..3
    const int m   = l & 15;
    const int qt  = blockIdx.x;        // 0..15
    const int h   = blockIdx.y;
    const int bz  = blockIdx.z;        // 0..15
    const int b   = bz >> 1;
    const int half = bz & 1;
    const int bh  = b * NHh + h;
    const int rowhalf = wv_ & 1;
    const int tileq   = wv_ >> 1;      // 0..1
    const int rowbase = qt * 64 + rowhalf * 32;
    const int tbase   = half * 8 + tileq * 4;

    // two q rows per lane (16 dw each): rows rowbase+m and rowbase+16+m
    unsigned qa[16], qb[16];
    {
        const uint4* qp = (const uint4*)qq8 + ((size_t)bh * TPAD + rowbase + m) * 4;
        *(uint4*)&qa[0]  = qp[0];  *(uint4*)&qa[4]  = qp[1];
        *(uint4*)&qa[8]  = qp[2];  *(uint4*)&qa[12] = qp[3];
        const uint4* qp2 = qp + 64;    // +16 rows
        *(uint4*)&qb[0]  = qp2[0]; *(uint4*)&qb[4]  = qp2[1];
        *(uint4*)&qb[8]  = qp2[2]; *(uint4*)&qb[12] = qp2[3];
    }

    const uint4* kg = (const uint4*)kq8 + (size_t)bh * 4096;  // tile t at +t*256
    const uint4* vg = vfrag + (size_t)bh * 8192;              // tile t at +t*512

    // stage k tiles (half*8 + I) and (half*8+4 + I) into buffer BUF; 2 GLDS per wave
#define STAGEK(I, BUF) do { \
        GLDS(kg + (half * 8 + (I)) * 256 + wv_ * 64 + l,     &smem[(0 * 2 + (BUF)) * 256 + wv_ * 64]); \
        GLDS(kg + (half * 8 + 4 + (I)) * 256 + wv_ * 64 + l, &smem[(1 * 2 + (BUF)) * 256 + wv_ * 64]); \
    } while (0)

    STAGEK(0, 0);
    __syncthreads();   // drains vmcnt

    f32x4 aca[4], acb[4];
#pragma unroll
    for (int n = 0; n < 4; ++n) { aca[n] = (f32x4){0.f,0.f,0.f,0.f}; acb[n] = aca[n]; }
    float dsum_a = 0.0f, dsum_b = 0.0f;

#pragma unroll 1
    for (int i = 0; i < 4; ++i) {
        const int cur = i & 1;
        const int t = tbase + i;                       // my source tile
        const uint4* kbase = &smem[(tileq * 2 + cur) * 256];
        const uint4* vt = vg + (size_t)t * 512 + l;

        if (i < 3) STAGEK(i + 1, cur ^ 1);

        // V fragments for kk=0 (latency hides under SADs)
        uint4 vf0 = vt[0 * 64], vf1 = vt[1 * 64], vf2 = vt[2 * 64], vf3 = vt[3 * 64];

        // ---- kk = 0 (never masked: local k-rows 0..31)
        bf16x8 Aa0, Ab0;
        {
            unsigned wa[4], wb[4];
            float pva = 0.f, pvb = 0.f;
#pragma unroll
            for (int e = 0; e < 8; ++e) {
                const uint4* kb = kbase + ((g << 3) + e) * 4;
                uint4 c0 = kb[0 ^ g], c1 = kb[1 ^ g], c2 = kb[2 ^ g], c3 = kb[3 ^ g];
                const unsigned* k0 = (const unsigned*)&c0;
                const unsigned* k1 = (const unsigned*)&c1;
                const unsigned* k2 = (const unsigned*)&c2;
                const unsigned* k3 = (const unsigned*)&c3;
                unsigned sa0 = 0u, sa1 = 0u, sb0 = 0u, sb1 = 0u;
#pragma unroll
                for (int w = 0; w < 4; ++w) {
                    sa0 = sad_u8(qa[w],      k0[w], sa0);
                    sa1 = sad_u8(qa[4 + w],  k1[w], sa1);
                    sb0 = sad_u8(qb[w],      k0[w], sb0);
                    sb1 = sad_u8(qb[4 + w],  k1[w], sb1);
                }
#pragma unroll
                for (int w = 0; w < 4; ++w) {
                    sa0 = sad_u8(qa[8 + w],  k2[w], sa0);
                    sa1 = sad_u8(qa[12 + w], k3[w], sa1);
                    sb0 = sad_u8(qb[8 + w],  k2[w], sb0);
                    sb1 = sad_u8(qb[12 + w], k3[w], sb1);
                }
                float pea = __builtin_amdgcn_exp2f(CQ * (float)(sa0 + sa1));
                float peb = __builtin_amdgcn_exp2f(CQ * (float)(sb0 + sb1));
                dsum_a += pea; dsum_b += peb;
                if (e & 1) { wa[e >> 1] = cvt_pk_bf16(pva, pea); wb[e >> 1] = cvt_pk_bf16(pvb, peb); }
                else       { pva = pea; pvb = peb; }
            }
            Aa0 = mkbf(wa[0], wa[1], wa[2], wa[3]);
            Ab0 = mkbf(wb[0], wb[1], wb[2], wb[3]);
        }

        aca[0] = __builtin_amdgcn_mfma_f32_16x16x32_bf16(Aa0, bfc(vf0), aca[0], 0, 0, 0);
        acb[0] = __builtin_amdgcn_mfma_f32_16x16x32_bf16(Ab0, bfc(vf0), acb[0], 0, 0, 0);
        aca[1] = __builtin_amdgcn_mfma_f32_16x16x32_bf16(Aa0, bfc(vf1), aca[1], 0, 0, 0);
        acb[1] = __builtin_amdgcn_mfma_f32_16x16x32_bf16(Ab0, bfc(vf1), acb[1], 0, 0, 0);
        aca[2] = __builtin_amdgcn_mfma_f32_16x16x32_bf16(Aa0, bfc(vf2), aca[2], 0, 0, 0);
        acb[2] = __builtin_amdgcn_mfma_f32_16x16x32_bf16(Ab0, bfc(vf2), acb[2], 0, 0, 0);
        aca[3] = __builtin_amdgcn_mfma_f32_16x16x32_bf16(Aa0, bfc(vf3), aca[3], 0, 0, 0);
        acb[3] = __builtin_amdgcn_mfma_f32_16x16x32_bf16(Ab0, bfc(vf3), acb[3], 0, 0, 0);

        // V fragments for kk=1
        uint4 vf4 = vt[4 * 64], vf5 = vt[5 * 64], vf6 = vt[6 * 64], vf7 = vt[7 * 64];

        // ---- kk = 1 (global tile 15 masks k-rows >= 1000: g>=1 range)
        bf16x8 Aa1, Ab1;
        {
            const bool maskall = (t == 15) && (g >= 1);
            unsigned wa[4], wb[4];
            float pva = 0.f, pvb = 0.f;
#pragma unroll
            for (int e = 0; e < 8; ++e) {
                const uint4* kb = kbase + (32 + (g << 3) + e) * 4;
                uint4 c0 = kb[0 ^ g], c1 = kb[1 ^ g], c2 = kb[2 ^ g], c3 = kb[3 ^ g];
                const unsigned* k0 = (const unsigned*)&c0;
                const unsigned* k1 = (const unsigned*)&c1;
                const unsigned* k2 = (const unsigned*)&c2;
                const unsigned* k3 = (const unsigned*)&c3;
                unsigned sa0 = 0u, sa1 = 0u, sb0 = 0u, sb1 = 0u;
#pragma unroll
                for (int w = 0; w < 4; ++w) {
                    sa0 = sad_u8(qa[w],      k0[w], sa0);
                    sa1 = sad_u8(qa[4 + w],  k1[w], sa1);
                    sb0 = sad_u8(qb[w],      k0[w], sb0);
                    sb1 = sad_u8(qb[4 + w],  k1[w], sb1);
                }
#pragma unroll
                for (int w = 0; w < 4; ++w) {
                    sa0 = sad_u8(qa[8 + w],  k2[w], sa0);
                    sa1 = sad_u8(qa[12 + w], k3[w], sa1);
                    sb0 = sad_u8(qb[8 + w],  k2[w], sb0);
                    sb1 = sad_u8(qb[12 + w], k3[w], sb1);
                }
                float pea = maskall ? 0.0f : __builtin_amdgcn_exp2f(CQ * (float)(sa0 + sa1));
                float peb = maskall ? 0.0f : __builtin_amdgcn_exp2f(CQ * (float)(sb0 + sb1));
                dsum_a += pea; dsum_b += peb;
                if (e & 1) { wa[e >> 1] = cvt_pk_bf16(pva, pea); wb[e >> 1] = cvt_pk_bf16(pvb, peb); }
                else       { pva = pea; pvb = peb; }
            }
            Aa1 = mkbf(wa[0], wa[1], wa[2], wa[3]);
            Ab1 = mkbf(wb[0], wb[1], wb[2], wb[3]);
        }

        aca[0] = __builtin_amdgcn_mfma_f32_16x16x32_bf16(Aa1, bfc(vf4), aca[0], 0, 0, 0);
        acb[0] = __builtin_amdgcn_mfma_f32_16x16x32_bf16(Ab1, bfc(vf4), acb[0], 0, 0, 0);
        aca[1] = __builtin_amdgcn_mfma_f32_16x16x32_bf16(Aa1, bfc(vf5), aca[1], 0, 0, 0);
        acb[1] = __builtin_amdgcn_mfma_f32_16x16x32_bf16(Ab1, bfc(vf5), acb[1], 0, 0, 0);
        aca[2] = __builtin_amdgcn_mfma_f32_16x16x32_bf16(Aa1, bfc(vf6), aca[2], 0, 0, 0);
        acb[2] = __builtin_amdgcn_mfma_f32_16x16x32_bf16(Ab1, bfc(vf6), acb[2], 0, 0, 0);
        aca[3] = __builtin_amdgcn_mfma_f32_16x16x32_bf16(Aa1, bfc(vf7), aca[3], 0, 0, 0);
        acb[3] = __builtin_amdgcn_mfma_f32_16x16x32_bf16(Ab1, bfc(vf7), acb[3], 0, 0, 0);

        __syncthreads();   // publishes next buffer; drains stages
    }
#undef STAGEK

    // intra-wave denominator reduce over the 4 lane-groups sharing m
    dsum_a += __shfl_xor(dsum_a, 16);
    dsum_a += __shfl_xor(dsum_a, 32);
    dsum_b += __shfl_xor(dsum_b, 16);
    dsum_b += __shfl_xor(dsum_b, 32);

    // cross-wave pair reduce (tileq 1 -> tileq 0) via LDS (reusing k-staging region)
    f32x4* red = (f32x4*)smem;         // [rowhalf][rowset][n][64] = 1024 f32x4 (16 KB)
    if (tileq == 1) {
#pragma unroll
        for (int n = 0; n < 4; ++n) {
            red[(((rowhalf * 2 + 0) * 4) + n) * 64 + l] = aca[n];
            red[(((rowhalf * 2 + 1) * 4) + n) * 64 + l] = acb[n];
        }
        if (l < 16) { dred[rowhalf][0][l] = dsum_a; dred[rowhalf][1][l] = dsum_b; }
    }
    __syncthreads();
    if (tileq == 0) {
#pragma unroll
        for (int n = 0; n < 4; ++n) {
            f32x4 ra = red[(((rowhalf * 2 + 0) * 4) + n) * 64 + l];
            f32x4 rb = red[(((rowhalf * 2 + 1) * 4) + n) * 64 + l];
#pragma unroll
            for (int j = 0; j < 4; ++j) { aca[n][j] += ra[j]; acb[n][j] += rb[j]; }
        }
        const float dta = dsum_a + dred[rowhalf][0][m];
        const float dtb = dsum_b + dred[rowhalf][1][m];

        // raw bf16 numerators: [(b*Tt+row)*16 + h*2+half][64]
#pragma unroll
        for (int j = 0; j < 4; ++j) {
            int row_a = rowbase + g * 4 + j;
            int row_b = rowbase + 16 + g * 4 + j;
            if (row_a < Tt) {
                unsigned short* o = numbf + (((size_t)(b * Tt + row_a) * 16) + h * 2 + half) * 64 + m;
                o[0]  = f2bf(aca[0][j]);
                o[16] = f2bf(aca[1][j]);
                o[32] = f2bf(aca[2][j]);
                o[48] = f2bf(aca[3][j]);
            }
            if (row_b < Tt) {
                unsigned short* o = numbf + (((size_t)(b * Tt + row_b) * 16) + h * 2 + half) * 64 + m;
                o[0]  = f2bf(acb[0][j]);
                o[16] = f2bf(acb[1][j]);
                o[32] = f2bf(acb[2][j]);
                o[48] = f2bf(acb[3][j]);
            }
        }
        // per-half denominator sums (without the +1 null term)
        if (l < 16) {
            int ra = rowbase + m, rb = rowbase + 16 + m;
            if (ra < Tt) dsums[(((size_t)(b * Tt + ra) * 8) + h) * 2 + half] = dta;
            if (rb < Tt) dsums[(((size_t)(b * Tt + rb) * 8) + h) * 2 + half] = dtb;
        }
    }
}

// ---------------- Kernel C: normalize + half/head-sum + ReLU + wf proj + residual ----
__global__ __launch_bounds__(256) void finalize_kernel(
    const float* __restrict__ x, const float* __restrict__ wf,
    const unsigned short* __restrict__ numbf, const float* __restrict__ dsums,
    float* __restrict__ out)
{
    __shared__ float wfs[64][65];
    __shared__ float osh[4][64];
    const int tid = threadIdx.x;
    for (int i = tid; i < 64 * 65; i += 256) wfs[i / 65][i % 65] = wf[i];
    const int wave = tid >> 6, lane = tid & 63;
    const int token = blockIdx.x * 4 + wave;   // 0..7999

    const float dsv = dsums[(size_t)token * 16 + (lane & 15)];
    const unsigned short* np = numbf + (size_t)token * 1024;
    float o = 0.f;
#pragma unroll
    for (int hh = 0; hh < 8; ++hh) {
        float den = 1.0f + __shfl(dsv, 2 * hh) + __shfl(dsv, 2 * hh + 1);
        float inv = 1.0f / den;
        float a0 = bf2f(np[(2 * hh) * 64 + lane]);
        float a1 = bf2f(np[(2 * hh + 1) * 64 + lane]);
        o += (a0 + a1) * inv;
    }
    o = fmaxf(o, 0.f);
    osh[wave][lane] = o;
    __syncthreads();
    float acc = wfs[lane][64];    // bias
#pragma unroll 8
    for (int w = 0; w < 64; ++w) acc += wfs[lane][w] * osh[wave][w];
    out[(size_t)token * Dd + lane] = x[(size_t)token * Dd + lane] + acc;
}

extern "C" void kernel_launch(void* const* d_in, const int* in_sizes, int n_in,
                              void* d_out, int out_size, void* d_ws, size_t ws_size,
                              hipStream_t stream)
{
    const float* x  = (const float*)d_in[0];
    const float* wq = (const float*)d_in[1];
    const float* wv = (const float*)d_in[2];
    const float* wk = (const float*)d_in[3];
    const float* wf = (const float*)d_in[4];
    float* out = (float*)d_out;

    char* base = (char*)d_ws;
    unsigned short* numbf = (unsigned short*)base;                    // 16,384,000 B
    float*    dsums = (float*)(base + 16384000);                      //    512,000 B
    unsigned* qq8   = (unsigned*)(base + 16896000);                   //  4,194,304 B
    unsigned* kq8   = (unsigned*)(base + 16896000 + 4194304);         //  4,194,304 B
    uint4*    vfrag = (uint4*)(base + 16896000 + 2 * 4194304);        //  8,388,608 B
    // total 33,673,216 B

    prep_kernel<<<dim3(16, 16, Bb), 256, 0, stream>>>(x, wq, wv, wk, qq8, kq8, vfrag);
    attn_kernel<<<dim3(16, NHh, 2 * Bb), 256, 0, stream>>>(qq8, kq8, vfrag, numbf, dsums);
    finalize_kernel<<<2000, 256, 0, stream>>>(x, wf, numbf, dsums, out);
}